// Round 11
// baseline (564.154 us; speedup 1.0000x reference)
//
#include <hip/hip_runtime.h>
#include <math.h>

// BEV deformable attention encoder, layer l = L-1 only.
// Round 11: MEASUREMENT ROUND. r10 refuted cooperative fusion (grid.sync
// cross-XCD coherence -> 3x HBM traffic, 290 vs 102 us). This is r8's proven
// 4-kernel path with runtime `reps` amplification per kernel so each dispatch
// exceeds the 40us harness-fill threshold and appears in top-5 with its own
// counters. reps is a runtime arg (compiler cannot fold the repeats); kernels
// are pure -> repeats idempotent & deterministic. Round 12 reverts reps=1.

#define NP 1600   // 40*40 query pixels
#define NJ 100    // 10*10 kv pixels

typedef _Float16 f16x8 __attribute__((ext_vector_type(8)));
typedef float  f32x4  __attribute__((ext_vector_type(4)));
typedef float  f32x2  __attribute__((ext_vector_type(2)));

template<int CTRL>
__device__ __forceinline__ float dpp_add(float x) {
  int y = __builtin_amdgcn_update_dpp(0, __builtin_bit_cast(int, x),
                                      CTRL, 0xf, 0xf, true);
  return x + __builtin_bit_cast(float, y);
}

// -------- grouped 1x1 conv (q): 8 groups; also writes transposed q_t -------
__global__ __launch_bounds__(256) void k_conv1x1(
    const float* __restrict__ x, const float* __restrict__ w,
    float* __restrict__ out, float* __restrict__ out_t, int reps) {
  int b = blockIdx.x;
  int g = b / 40;
  int r = b - g * 40;
  int oc = r / 5;
  int p0 = (r - oc * 5) * 320;
  int co0 = g * 64 + oc * 8;
  const float* xg = x + g * 32 * NP;
  const float* wr = w + co0 * 32;   // block-uniform -> scalar loads
  for (int rep = 0; rep < reps; ++rep) {
    for (int p = p0 + threadIdx.x; p < p0 + 320; p += 256) {
      float acc[8];
#pragma unroll
      for (int o = 0; o < 8; ++o) acc[o] = 0.f;
#pragma unroll
      for (int ci = 0; ci < 32; ++ci) {
        float xv = xg[ci * NP + p];
#pragma unroll
        for (int o = 0; o < 8; ++o) acc[o] = fmaf(wr[o * 32 + ci], xv, acc[o]);
      }
#pragma unroll
      for (int o = 0; o < 8; ++o) out[(co0 + o) * NP + p] = acc[o];
      f32x4 t0, t1;
      t0[0] = acc[0]; t0[1] = acc[1]; t0[2] = acc[2]; t0[3] = acc[3];
      t1[0] = acc[4]; t1[1] = acc[5]; t1[2] = acc[6]; t1[3] = acc[7];
      *(f32x4*)(out_t + (size_t)p * 512 + co0) = t0;
      *(f32x4*)(out_t + (size_t)p * 512 + co0 + 4) = t1;
    }
  }
}

// ------ fused: dw 6x6 s4 + gelu + pw + tanh + grid + sample + k/v conv
//        + fp16 layer-1 tables + CPB MFMA. One block per gj (800 blocks). ----
__global__ __launch_bounds__(256, 4) void k_off_cpb(
    const float* __restrict__ qt, const float* __restrict__ wdw,
    const float* __restrict__ bdw, const float* __restrict__ wo2,
    const float* __restrict__ x, const float* __restrict__ wk,
    const float* __restrict__ wv,
    const float* __restrict__ w0, const float* __restrict__ b0,
    const float* __restrict__ w1, const float* __restrict__ b1v,
    const float* __restrict__ cw2, const float* __restrict__ b2,
    float* __restrict__ kout, float* __restrict__ vout_t,
    float* __restrict__ bias_t, int reps) {
  __shared__ float psum[4][72];
  __shared__ float su_l[40];
  __shared__ float sv_l[40];
  __shared__ _Float16 a16[40][72];
  __shared__ _Float16 c16[40][72];
  int gj = blockIdx.x;
  int g = gj / 100;
  int j = gj - g * 100;
  int t = threadIdx.x;
  int lane = t & 63;
  int wv_id = t >> 6;
  int oy = j / 10, ox = j - (j / 10) * 10;
  int row = lane & 15;
  int kgrp = lane >> 4;
  // rep-invariant CPB constants
  f16x8 B[4][2];
#pragma unroll
  for (int ct = 0; ct < 4; ++ct)
#pragma unroll
    for (int s = 0; s < 2; ++s)
#pragma unroll
      for (int e = 0; e < 8; ++e)
        B[ct][s][e] = (_Float16)w1[(ct * 16 + row) * 64 + s * 32 + kgrp * 8 + e];
  float b1c[4], w2c[4];
#pragma unroll
  for (int ct = 0; ct < 4; ++ct) {
    b1c[ct] = b1v[ct * 16 + row];
    w2c[ct] = cw2[ct * 16 + row];
  }
  float bb = b2[0];
  float* outp = bias_t + (size_t)gj * 1600;
  f16x8 zero8 = {};

  for (int rep = 0; rep < reps; ++rep) {
    // dw-conv partials: wave handles taps wv_id*9..+8; lane = d
    {
      float acc = 0.f;
      const float* qrow = qt + g * 64 + lane;
#pragma unroll
      for (int tu = 0; tu < 9; ++tu) {
        int tt = wv_id * 9 + tu;
        int ky = tt / 6, kx = tt - (tt / 6) * 6;
        int iy = oy * 4 - 1 + ky;
        int ix = ox * 4 - 1 + kx;
        if (iy >= 0 && iy < 40 && ix >= 0 && ix < 40)
          acc = fmaf(wdw[lane * 36 + tt], qrow[(size_t)(iy * 40 + ix) * 512], acc);
      }
      psum[wv_id][lane] = acc;
    }
    __syncthreads();

    // wave 0: gelu -> pw -> tanh*4 -> grid -> sample -> k/v conv
    if (wv_id == 0) {
      float accd = psum[0][lane] + psum[1][lane] + psum[2][lane] + psum[3][lane]
                 + bdw[lane];
      float od = 0.5f * accd * (1.0f + erff(accd * 0.70710678118654752440f));
      float px = wo2[lane] * od, py = wo2[64 + lane] * od;
#pragma unroll
      for (int m = 1; m < 64; m <<= 1) {
        px += __shfl_xor(px, m);
        py += __shfl_xor(py, m);
      }
      float ax = tanhf(px) * 4.f;
      float ay = tanhf(py) * 4.f;
      float vx = (float)ox + ax;
      float vy = (float)oy + ay;
      float g0 = 2.f * vx / 9.f - 1.f;
      float g1 = 2.f * vy / 9.f - 1.f;
      if (lane < 40) {
        float qc = (float)lane * (2.f / 39.f) - 1.f;
        float u = qc - g0;
        float vv2 = qc - g1;
        su_l[lane] = copysignf(log1pf(fabsf(u)), u);
        sv_l[lane] = copysignf(log1pf(fabsf(vv2)), vv2);
      }
      float gx = ((g0 + 1.f) * 40.f - 1.f) * 0.5f;
      float gy = ((g1 + 1.f) * 40.f - 1.f) * 0.5f;
      float x0f = floorf(gx), y0f = floorf(gy);
      float wx = gx - x0f, wy = gy - y0f;
      bool mx0 = (x0f >= 0.f) && (x0f <= 39.f);
      bool mx1 = (x0f + 1.f >= 0.f) && (x0f + 1.f <= 39.f);
      bool my0 = (y0f >= 0.f) && (y0f <= 39.f);
      bool my1 = (y0f + 1.f >= 0.f) && (y0f + 1.f <= 39.f);
      int ix0 = (int)fminf(fmaxf(x0f, 0.f), 39.f);
      int ix1 = (int)fminf(fmaxf(x0f + 1.f, 0.f), 39.f);
      int iy0 = (int)fminf(fmaxf(y0f, 0.f), 39.f);
      int iy1 = (int)fminf(fmaxf(y0f + 1.f, 0.f), 39.f);
      float w00 = (1.f - wx) * (1.f - wy) * ((mx0 && my0) ? 1.f : 0.f);
      float w10 = wx * (1.f - wy) * ((mx1 && my0) ? 1.f : 0.f);
      float w01 = (1.f - wx) * wy * ((mx0 && my1) ? 1.f : 0.f);
      float w11 = wx * wy * ((mx1 && my1) ? 1.f : 0.f);
      int b00 = iy0 * 40 + ix0, b10 = iy0 * 40 + ix1;
      int b01 = iy1 * 40 + ix0, b11 = iy1 * 40 + ix1;
      float kvc = 0.f;
      if (lane < 32) {
        const float* xc = x + (g * 32 + lane) * NP;
        kvc = w00 * xc[b00] + w10 * xc[b10] + w01 * xc[b01] + w11 * xc[b11];
      }
      const float* wkr = wk + (g * 64 + lane) * 32;
      const float* wvr = wv + (g * 64 + lane) * 32;
      float wkreg[32], wvreg[32];
#pragma unroll
      for (int q4 = 0; q4 < 8; ++q4) {
        f32x4 a = *(const f32x4*)(wkr + q4 * 4);
        f32x4 bq = *(const f32x4*)(wvr + q4 * 4);
#pragma unroll
        for (int e = 0; e < 4; ++e) { wkreg[q4 * 4 + e] = a[e]; wvreg[q4 * 4 + e] = bq[e]; }
      }
      float kacc = 0.f, vacc = 0.f;
#pragma unroll
      for (int c = 0; c < 32; ++c) {
        float kvb = __shfl(kvc, c);
        kacc = fmaf(wkreg[c], kvb, kacc);
        vacc = fmaf(wvreg[c], kvb, vacc);
      }
      kout[(g * 64 + lane) * 100 + j] = kacc;
      vout_t[(size_t)gj * 64 + lane] = vacc;     // transposed, coalesced
    }
    __syncthreads();

    // fp16 layer-1 tables (all waves)
    for (int idx = t; idx < 2560; idx += 256) {
      int xi = idx >> 6, kk = idx & 63;
      a16[xi][kk] = (_Float16)fmaf(w0[2 * kk], su_l[xi], b0[kk]);
      c16[xi][kk] = (_Float16)(w0[2 * kk + 1] * sv_l[xi]);
    }
    __syncthreads();

    // cpb MFMA: per-wave 25 tiles
    int it0 = wv_id * 25;
    int iy = wv_id * 10;
    int ix = row;
    for (int it = it0; it < it0 + 25; ++it) {
      f32x4 acc[4];
#pragma unroll
      for (int ct = 0; ct < 4; ++ct) {
        acc[ct][0] = 0.f; acc[ct][1] = 0.f; acc[ct][2] = 0.f; acc[ct][3] = 0.f;
      }
#pragma unroll
      for (int s = 0; s < 2; ++s) {
        f16x8 av = *(const f16x8*)&a16[ix][s * 32 + kgrp * 8];
        f16x8 cv = *(const f16x8*)&c16[iy][s * 32 + kgrp * 8];
        f16x8 A = __builtin_elementwise_max(av + cv, zero8);
#pragma unroll
        for (int ct = 0; ct < 4; ++ct)
          acc[ct] = __builtin_amdgcn_mfma_f32_16x16x32_f16(A, B[ct][s], acc[ct], 0, 0, 0);
      }
      float part[4];
#pragma unroll
      for (int ri = 0; ri < 4; ++ri) {
        float s2 = 0.f;
#pragma unroll
        for (int ct = 0; ct < 4; ++ct) {
          float val = acc[ct][ri] + b1c[ct];
          s2 = fmaf(w2c[ct], fmaxf(val, 0.f), s2);
        }
        part[ri] = s2;
      }
#pragma unroll
      for (int ri = 0; ri < 4; ++ri) {
        part[ri] = dpp_add<0xB1>(part[ri]);    // quad_perm [1,0,3,2]
        part[ri] = dpp_add<0x4E>(part[ri]);    // quad_perm [2,3,0,1]
        part[ri] = dpp_add<0x141>(part[ri]);   // row_half_mirror
        part[ri] = dpp_add<0x140>(part[ri]);   // row_mirror
      }
      if (row == 0) {
        f32x4 o;
        o[0] = part[0] + bb; o[1] = part[1] + bb;
        o[2] = part[2] + bb; o[3] = part[3] + bb;
        *(f32x4*)(outp + it * 16 + kgrp * 4) = o;
      }
      ix += 16;
      if (ix >= 40) { ix -= 40; ++iy; }
    }
    __syncthreads();   // protect LDS for next rep
  }
}

// ---------------- fused attention: i-tile 16, 800 blocks -------------------
__global__ __launch_bounds__(256) void k_attn(
    const float* __restrict__ q, const float* __restrict__ k,
    const float* __restrict__ v_t, const float* __restrict__ bias_t,
    float* __restrict__ inner, int reps) {
  __shared__ float v_lds[100][68];
  __shared__ float s_lds[16][100];
  int h = blockIdx.x / 100;
  int i0 = (blockIdx.x - h * 100) * 16;
  int t = threadIdx.x;
  for (int rep = 0; rep < reps; ++rep) {
    for (int idx = t; idx < 6400; idx += 256) {
      int j = idx >> 6, d = idx & 63;
      v_lds[j][d] = v_t[(size_t)h * 6400 + idx];
    }
    __syncthreads();
    if (t < 200) {
      int ib = (t / 25) * 2, jb = (t % 25) * 4;
      const float* qp = q + h * 64 * NP + i0 + ib;
      const float* kp = k + h * 64 * 100 + jb;
      float a[2][4];
#pragma unroll
      for (int ii = 0; ii < 2; ++ii)
#pragma unroll
        for (int jj = 0; jj < 4; ++jj) a[ii][jj] = 0.f;
#pragma unroll 8
      for (int d = 0; d < 64; ++d) {
        f32x2 qv = *(const f32x2*)(qp + d * NP);
        f32x4 kv4 = *(const f32x4*)(kp + d * 100);
#pragma unroll
        for (int ii = 0; ii < 2; ++ii)
#pragma unroll
          for (int jj = 0; jj < 4; ++jj)
            a[ii][jj] = fmaf(qv[ii], kv4[jj], a[ii][jj]);
      }
      const float* bcol = bias_t + (size_t)h * 100 * 1600;
#pragma unroll
      for (int jj = 0; jj < 4; ++jj) {
        f32x2 bv = *(const f32x2*)(bcol + (size_t)(jb + jj) * 1600 + i0 + ib);
#pragma unroll
        for (int ii = 0; ii < 2; ++ii)
          s_lds[ib + ii][jb + jj] = fmaf(a[ii][jj], 0.125f, bv[ii]);
      }
    }
    __syncthreads();
    {
      int i = t >> 4, sub = t & 15;
      float m = -1e30f;
      for (int j = sub; j < 100; j += 16) m = fmaxf(m, s_lds[i][j]);
#pragma unroll
      for (int off = 1; off < 16; off <<= 1) m = fmaxf(m, __shfl_xor(m, off));
      float sum = 0.f;
      for (int j = sub; j < 100; j += 16) {
        float e = expf(s_lds[i][j] - m);
        s_lds[i][j] = e;
        sum += e;
      }
#pragma unroll
      for (int off = 1; off < 16; off <<= 1) sum += __shfl_xor(sum, off);
      float inv = 1.f / sum;
      for (int j = sub; j < 100; j += 16) s_lds[i][j] *= inv;
    }
    __syncthreads();
    {
      int i = t & 15, db = (t >> 4) * 4;
      float acc[4];
#pragma unroll
      for (int dd = 0; dd < 4; ++dd) acc[dd] = 0.f;
      for (int jc = 0; jc < 25; ++jc) {
        f32x4 sv = *(const f32x4*)&s_lds[i][jc * 4];
#pragma unroll
        for (int jj = 0; jj < 4; ++jj) {
          f32x4 vv = *(const f32x4*)&v_lds[jc * 4 + jj][db];
#pragma unroll
          for (int dd = 0; dd < 4; ++dd)
            acc[dd] = fmaf(sv[jj], vv[dd], acc[dd]);
        }
      }
#pragma unroll
      for (int dd = 0; dd < 4; ++dd)
        inner[(h * 64 + db + dd) * NP + i0 + i] = acc[dd];
    }
    __syncthreads();   // protect LDS for next rep
  }
}

// ---------------- output projection 256x512 @ 512x1600 + bias --------------
__global__ __launch_bounds__(256) void k_proj(
    const float* __restrict__ inner, const float* __restrict__ w,
    const float* __restrict__ bo, float* __restrict__ out, int reps) {
  int ot = blockIdx.x / 25;
  int pt = blockIdx.x - ot * 25;
  int t = threadIdx.x;
  int quad = __builtin_amdgcn_readfirstlane(t >> 6);  // wave-uniform
  int o0 = ot * 16 + quad * 4;
  int p = pt * 64 + (t & 63);
  const float* w0r = w + o0 * 512;   // wave-uniform -> scalar loads
  for (int rep = 0; rep < reps; ++rep) {
    float a0 = 0.f, a1 = 0.f, a2 = 0.f, a3 = 0.f;
#pragma unroll 8
    for (int c = 0; c < 512; ++c) {
      float xv = inner[c * NP + p];
      a0 = fmaf(w0r[c], xv, a0);
      a1 = fmaf(w0r[512 + c], xv, a1);
      a2 = fmaf(w0r[1024 + c], xv, a2);
      a3 = fmaf(w0r[1536 + c], xv, a3);
    }
    out[(o0 + 0) * NP + p] = a0 + bo[o0 + 0];
    out[(o0 + 1) * NP + p] = a1 + bo[o0 + 1];
    out[(o0 + 2) * NP + p] = a2 + bo[o0 + 2];
    out[(o0 + 3) * NP + p] = a3 + bo[o0 + 3];
  }
}

extern "C" void kernel_launch(void* const* d_in, const int* in_sizes, int n_in,
                              void* d_out, int out_size, void* d_ws, size_t ws_size,
                              hipStream_t stream) {
  int L = in_sizes[1] / (512 * 32);
  int l = L - 1;
  const float* x      = (const float*)d_in[0];
  const float* wq     = (const float*)d_in[1]  + (size_t)l * 512 * 32;
  const float* wk     = (const float*)d_in[2]  + (size_t)l * 512 * 32;
  const float* wv     = (const float*)d_in[3]  + (size_t)l * 512 * 32;
  const float* w_off1 = (const float*)d_in[4]  + (size_t)l * 64 * 36;
  const float* b_off1 = (const float*)d_in[5]  + (size_t)l * 64;
  const float* w_off2 = (const float*)d_in[6]  + (size_t)l * 2 * 64;
  const float* cpb_w0 = (const float*)d_in[7]  + (size_t)l * 64 * 2;
  const float* cpb_b0 = (const float*)d_in[8]  + (size_t)l * 64;
  const float* cpb_w1 = (const float*)d_in[9]  + (size_t)l * 64 * 64;
  const float* cpb_b1 = (const float*)d_in[10] + (size_t)l * 64;
  const float* cpb_w2 = (const float*)d_in[11] + (size_t)l * 64;
  const float* cpb_b2 = (const float*)d_in[12] + (size_t)l * 1;
  const float* w_out  = (const float*)d_in[13] + (size_t)l * 256 * 512;
  const float* b_out  = (const float*)d_in[14] + (size_t)l * 256;
  float* out = (float*)d_out;

  float* ws = (float*)d_ws;
  float* q_ws    = ws;               // 819200
  float* qt_ws   = ws + 819200;      // 819200 (transposed [p][512])
  float* k_ws    = ws + 1638400;     // 51200
  float* vt_ws   = ws + 1689600;     // 51200 (transposed [gj][c])
  float* bias_t  = ws + 1740800;     // 1280000 (transposed [gj][i])
  float* inner   = ws + 3020800;     // 819200  (end 3,840,000 f = 15.36 MB)

  // Amplification factors (measurement round): each amplified dispatch must
  // exceed the ~40us fill threshold to appear in top-5 with its counters.
  k_conv1x1<<<320, 256, 0, stream>>>(x, wq, q_ws, qt_ws, 12);
  k_off_cpb<<<800, 256, 0, stream>>>(qt_ws, w_off1, b_off1, w_off2, x, wk, wv,
                                     cpb_w0, cpb_b0, cpb_w1, cpb_b1, cpb_w2,
                                     cpb_b2, k_ws, vt_ws, bias_t, 6);
  k_attn<<<800, 256, 0, stream>>>(q_ws, k_ws, vt_ws, bias_t, inner, 6);
  k_proj<<<400, 256, 0, stream>>>(inner, w_out, b_out, out, 10);
}

// Round 12
// 98.981 us; speedup vs baseline: 5.6996x; 5.6996x over previous
//
#include <hip/hip_runtime.h>
#include <math.h>

// BEV deformable attention encoder, layer l = L-1 only.
// Round 12: measured r11 breakdown (off_cpb 34us mem-bound, proj 20us
// latency-bound, attn 15, conv 4). Fixes: (1) XCD-aware remap in off_cpb
// (g = b&7 -> one group per XCD L2, kills 13MB/rep cross-XCD qt re-fetch);
// (2) bias_t stored fp16 (10.2 -> 5.1 MB traffic); (3) proj 800 blocks,
// 2 couts/thread (occupancy 16% -> ~40%). reps reverted to 1.

#define NP 1600   // 40*40 query pixels
#define NJ 100    // 10*10 kv pixels

typedef _Float16 f16x8 __attribute__((ext_vector_type(8)));
typedef _Float16 f16x4 __attribute__((ext_vector_type(4)));
typedef _Float16 f16x2 __attribute__((ext_vector_type(2)));
typedef float  f32x4  __attribute__((ext_vector_type(4)));
typedef float  f32x2  __attribute__((ext_vector_type(2)));

template<int CTRL>
__device__ __forceinline__ float dpp_add(float x) {
  int y = __builtin_amdgcn_update_dpp(0, __builtin_bit_cast(int, x),
                                      CTRL, 0xf, 0xf, true);
  return x + __builtin_bit_cast(float, y);
}

// -------- grouped 1x1 conv (q): 8 groups; also writes transposed q_t -------
__global__ __launch_bounds__(256) void k_conv1x1(
    const float* __restrict__ x, const float* __restrict__ w,
    float* __restrict__ out, float* __restrict__ out_t) {
  int b = blockIdx.x;
  int g = b / 40;
  int r = b - g * 40;
  int oc = r / 5;
  int p0 = (r - oc * 5) * 320;
  int co0 = g * 64 + oc * 8;
  const float* xg = x + g * 32 * NP;
  const float* wr = w + co0 * 32;   // block-uniform -> scalar loads
  for (int p = p0 + threadIdx.x; p < p0 + 320; p += 256) {
    float acc[8];
#pragma unroll
    for (int o = 0; o < 8; ++o) acc[o] = 0.f;
#pragma unroll
    for (int ci = 0; ci < 32; ++ci) {
      float xv = xg[ci * NP + p];
#pragma unroll
      for (int o = 0; o < 8; ++o) acc[o] = fmaf(wr[o * 32 + ci], xv, acc[o]);
    }
#pragma unroll
    for (int o = 0; o < 8; ++o) out[(co0 + o) * NP + p] = acc[o];
    f32x4 t0, t1;
    t0[0] = acc[0]; t0[1] = acc[1]; t0[2] = acc[2]; t0[3] = acc[3];
    t1[0] = acc[4]; t1[1] = acc[5]; t1[2] = acc[6]; t1[3] = acc[7];
    *(f32x4*)(out_t + (size_t)p * 512 + co0) = t0;
    *(f32x4*)(out_t + (size_t)p * 512 + co0 + 4) = t1;
  }
}

// ------ fused: dw 6x6 s4 + gelu + pw + tanh + grid + sample + k/v conv
//        + fp16 layer-1 tables + CPB MFMA. One block per gj; XCD-remapped:
//        g = b&7 (one group per XCD L2), j = b>>3. --------------------------
__global__ __launch_bounds__(256, 4) void k_off_cpb(
    const float* __restrict__ qt, const float* __restrict__ wdw,
    const float* __restrict__ bdw, const float* __restrict__ wo2,
    const float* __restrict__ x, const float* __restrict__ wk,
    const float* __restrict__ wv,
    const float* __restrict__ w0, const float* __restrict__ b0,
    const float* __restrict__ w1, const float* __restrict__ b1v,
    const float* __restrict__ cw2, const float* __restrict__ b2,
    float* __restrict__ kout, float* __restrict__ vout_t,
    _Float16* __restrict__ bias16) {
  __shared__ float psum[4][72];
  __shared__ float su_l[40];
  __shared__ float sv_l[40];
  __shared__ _Float16 a16[40][72];
  __shared__ _Float16 c16[40][72];
  int b = blockIdx.x;
  int g = b & 7;          // XCD-aware: b%8 -> XCD round-robin -> 1 group/XCD
  int j = b >> 3;         // 0..99
  int gj = g * 100 + j;   // semantic column id (output layout unchanged)
  int t = threadIdx.x;
  int lane = t & 63;
  int wv_id = t >> 6;
  int oy = j / 10, ox = j - (j / 10) * 10;
  int row = lane & 15;
  int kgrp = lane >> 4;

  // dw-conv partials: wave handles taps wv_id*9..+8; lane = d
  {
    float acc = 0.f;
    const float* qrow = qt + g * 64 + lane;
#pragma unroll
    for (int tu = 0; tu < 9; ++tu) {
      int tt = wv_id * 9 + tu;
      int ky = tt / 6, kx = tt - (tt / 6) * 6;
      int iy = oy * 4 - 1 + ky;
      int ix = ox * 4 - 1 + kx;
      if (iy >= 0 && iy < 40 && ix >= 0 && ix < 40)
        acc = fmaf(wdw[lane * 36 + tt], qrow[(size_t)(iy * 40 + ix) * 512], acc);
    }
    psum[wv_id][lane] = acc;
  }
  __syncthreads();

  // wave 0: gelu -> pw -> tanh*4 -> grid -> sample -> k/v conv
  if (wv_id == 0) {
    float accd = psum[0][lane] + psum[1][lane] + psum[2][lane] + psum[3][lane]
               + bdw[lane];
    float od = 0.5f * accd * (1.0f + erff(accd * 0.70710678118654752440f));
    float px = wo2[lane] * od, py = wo2[64 + lane] * od;
#pragma unroll
    for (int m = 1; m < 64; m <<= 1) {
      px += __shfl_xor(px, m);
      py += __shfl_xor(py, m);
    }
    float ax = tanhf(px) * 4.f;
    float ay = tanhf(py) * 4.f;
    float vx = (float)ox + ax;
    float vy = (float)oy + ay;
    float g0 = 2.f * vx / 9.f - 1.f;
    float g1 = 2.f * vy / 9.f - 1.f;
    if (lane < 40) {
      float qc = (float)lane * (2.f / 39.f) - 1.f;
      float u = qc - g0;
      float vv2 = qc - g1;
      su_l[lane] = copysignf(log1pf(fabsf(u)), u);
      sv_l[lane] = copysignf(log1pf(fabsf(vv2)), vv2);
    }
    float gx = ((g0 + 1.f) * 40.f - 1.f) * 0.5f;
    float gy = ((g1 + 1.f) * 40.f - 1.f) * 0.5f;
    float x0f = floorf(gx), y0f = floorf(gy);
    float wx = gx - x0f, wy = gy - y0f;
    bool mx0 = (x0f >= 0.f) && (x0f <= 39.f);
    bool mx1 = (x0f + 1.f >= 0.f) && (x0f + 1.f <= 39.f);
    bool my0 = (y0f >= 0.f) && (y0f <= 39.f);
    bool my1 = (y0f + 1.f >= 0.f) && (y0f + 1.f <= 39.f);
    int ix0 = (int)fminf(fmaxf(x0f, 0.f), 39.f);
    int ix1 = (int)fminf(fmaxf(x0f + 1.f, 0.f), 39.f);
    int iy0 = (int)fminf(fmaxf(y0f, 0.f), 39.f);
    int iy1 = (int)fminf(fmaxf(y0f + 1.f, 0.f), 39.f);
    float w00 = (1.f - wx) * (1.f - wy) * ((mx0 && my0) ? 1.f : 0.f);
    float w10 = wx * (1.f - wy) * ((mx1 && my0) ? 1.f : 0.f);
    float w01 = (1.f - wx) * wy * ((mx0 && my1) ? 1.f : 0.f);
    float w11 = wx * wy * ((mx1 && my1) ? 1.f : 0.f);
    int b00 = iy0 * 40 + ix0, b10 = iy0 * 40 + ix1;
    int b01 = iy1 * 40 + ix0, b11 = iy1 * 40 + ix1;
    float kvc = 0.f;
    if (lane < 32) {
      const float* xc = x + (g * 32 + lane) * NP;
      kvc = w00 * xc[b00] + w10 * xc[b10] + w01 * xc[b01] + w11 * xc[b11];
    }
    const float* wkr = wk + (g * 64 + lane) * 32;
    const float* wvr = wv + (g * 64 + lane) * 32;
    float wkreg[32], wvreg[32];
#pragma unroll
    for (int q4 = 0; q4 < 8; ++q4) {
      f32x4 a = *(const f32x4*)(wkr + q4 * 4);
      f32x4 bq = *(const f32x4*)(wvr + q4 * 4);
#pragma unroll
      for (int e = 0; e < 4; ++e) { wkreg[q4 * 4 + e] = a[e]; wvreg[q4 * 4 + e] = bq[e]; }
    }
    float kacc = 0.f, vacc = 0.f;
#pragma unroll
    for (int c = 0; c < 32; ++c) {
      float kvb = __shfl(kvc, c);
      kacc = fmaf(wkreg[c], kvb, kacc);
      vacc = fmaf(wvreg[c], kvb, vacc);
    }
    kout[(g * 64 + lane) * 100 + j] = kacc;
    vout_t[(size_t)gj * 64 + lane] = vacc;     // transposed, coalesced
  }
  __syncthreads();

  // fp16 layer-1 tables (all waves)
  for (int idx = t; idx < 2560; idx += 256) {
    int xi = idx >> 6, kk = idx & 63;
    a16[xi][kk] = (_Float16)fmaf(w0[2 * kk], su_l[xi], b0[kk]);
    c16[xi][kk] = (_Float16)(w0[2 * kk + 1] * sv_l[xi]);
  }

  // cpb MFMA: B frags + per-wave 25 tiles
  f16x8 B[4][2];
#pragma unroll
  for (int ct = 0; ct < 4; ++ct)
#pragma unroll
    for (int s = 0; s < 2; ++s)
#pragma unroll
      for (int e = 0; e < 8; ++e)
        B[ct][s][e] = (_Float16)w1[(ct * 16 + row) * 64 + s * 32 + kgrp * 8 + e];
  float b1c[4], w2c[4];
#pragma unroll
  for (int ct = 0; ct < 4; ++ct) {
    b1c[ct] = b1v[ct * 16 + row];
    w2c[ct] = cw2[ct * 16 + row];
  }
  float bb = b2[0];
  _Float16* outp = bias16 + (size_t)gj * 1600;
  __syncthreads();

  int it0 = wv_id * 25;
  int iy = wv_id * 10;
  int ix = row;
  f16x8 zero8 = {};
  for (int it = it0; it < it0 + 25; ++it) {
    f32x4 acc[4];
#pragma unroll
    for (int ct = 0; ct < 4; ++ct) {
      acc[ct][0] = 0.f; acc[ct][1] = 0.f; acc[ct][2] = 0.f; acc[ct][3] = 0.f;
    }
#pragma unroll
    for (int s = 0; s < 2; ++s) {
      f16x8 av = *(const f16x8*)&a16[ix][s * 32 + kgrp * 8];
      f16x8 cv = *(const f16x8*)&c16[iy][s * 32 + kgrp * 8];
      f16x8 A = __builtin_elementwise_max(av + cv, zero8);
#pragma unroll
      for (int ct = 0; ct < 4; ++ct)
        acc[ct] = __builtin_amdgcn_mfma_f32_16x16x32_f16(A, B[ct][s], acc[ct], 0, 0, 0);
    }
    float part[4];
#pragma unroll
    for (int ri = 0; ri < 4; ++ri) {
      float s2 = 0.f;
#pragma unroll
      for (int ct = 0; ct < 4; ++ct) {
        float val = acc[ct][ri] + b1c[ct];
        s2 = fmaf(w2c[ct], fmaxf(val, 0.f), s2);
      }
      part[ri] = s2;
    }
#pragma unroll
    for (int ri = 0; ri < 4; ++ri) {
      part[ri] = dpp_add<0xB1>(part[ri]);    // quad_perm [1,0,3,2]
      part[ri] = dpp_add<0x4E>(part[ri]);    // quad_perm [2,3,0,1]
      part[ri] = dpp_add<0x141>(part[ri]);   // row_half_mirror
      part[ri] = dpp_add<0x140>(part[ri]);   // row_mirror
    }
    if (row == 0) {
      f16x4 o;
      o[0] = (_Float16)(part[0] + bb); o[1] = (_Float16)(part[1] + bb);
      o[2] = (_Float16)(part[2] + bb); o[3] = (_Float16)(part[3] + bb);
      *(f16x4*)(outp + it * 16 + kgrp * 4) = o;
    }
    ix += 16;
    if (ix >= 40) { ix -= 40; ++iy; }
  }
}

// ---------------- fused attention: i-tile 16, 800 blocks, fp16 bias --------
__global__ __launch_bounds__(256) void k_attn(
    const float* __restrict__ q, const float* __restrict__ k,
    const float* __restrict__ v_t, const _Float16* __restrict__ bias16,
    float* __restrict__ inner) {
  __shared__ float v_lds[100][68];
  __shared__ float s_lds[16][100];
  int h = blockIdx.x / 100;
  int i0 = (blockIdx.x - h * 100) * 16;
  int t = threadIdx.x;
  for (int idx = t; idx < 6400; idx += 256) {
    int j = idx >> 6, d = idx & 63;
    v_lds[j][d] = v_t[(size_t)h * 6400 + idx];
  }
  __syncthreads();
  if (t < 200) {
    int ib = (t / 25) * 2, jb = (t % 25) * 4;
    const float* qp = q + h * 64 * NP + i0 + ib;
    const float* kp = k + h * 64 * 100 + jb;
    float a[2][4];
#pragma unroll
    for (int ii = 0; ii < 2; ++ii)
#pragma unroll
      for (int jj = 0; jj < 4; ++jj) a[ii][jj] = 0.f;
#pragma unroll 8
    for (int d = 0; d < 64; ++d) {
      f32x2 qv = *(const f32x2*)(qp + d * NP);
      f32x4 kv4 = *(const f32x4*)(kp + d * 100);
#pragma unroll
      for (int ii = 0; ii < 2; ++ii)
#pragma unroll
        for (int jj = 0; jj < 4; ++jj)
          a[ii][jj] = fmaf(qv[ii], kv4[jj], a[ii][jj]);
    }
    const _Float16* bcol = bias16 + (size_t)h * 100 * 1600;
#pragma unroll
    for (int jj = 0; jj < 4; ++jj) {
      f16x2 bv = *(const f16x2*)(bcol + (size_t)(jb + jj) * 1600 + i0 + ib);
#pragma unroll
      for (int ii = 0; ii < 2; ++ii)
        s_lds[ib + ii][jb + jj] = fmaf(a[ii][jj], 0.125f, (float)bv[ii]);
    }
  }
  __syncthreads();
  {
    int i = t >> 4, sub = t & 15;
    float m = -1e30f;
    for (int j = sub; j < 100; j += 16) m = fmaxf(m, s_lds[i][j]);
#pragma unroll
    for (int off = 1; off < 16; off <<= 1) m = fmaxf(m, __shfl_xor(m, off));
    float sum = 0.f;
    for (int j = sub; j < 100; j += 16) {
      float e = expf(s_lds[i][j] - m);
      s_lds[i][j] = e;
      sum += e;
    }
#pragma unroll
    for (int off = 1; off < 16; off <<= 1) sum += __shfl_xor(sum, off);
    float inv = 1.f / sum;
    for (int j = sub; j < 100; j += 16) s_lds[i][j] *= inv;
  }
  __syncthreads();
  {
    int i = t & 15, db = (t >> 4) * 4;
    float acc[4];
#pragma unroll
    for (int dd = 0; dd < 4; ++dd) acc[dd] = 0.f;
    for (int jc = 0; jc < 25; ++jc) {
      f32x4 sv = *(const f32x4*)&s_lds[i][jc * 4];
#pragma unroll
      for (int jj = 0; jj < 4; ++jj) {
        f32x4 vv = *(const f32x4*)&v_lds[jc * 4 + jj][db];
#pragma unroll
        for (int dd = 0; dd < 4; ++dd)
          acc[dd] = fmaf(sv[jj], vv[dd], acc[dd]);
      }
    }
#pragma unroll
    for (int dd = 0; dd < 4; ++dd)
      inner[(h * 64 + db + dd) * NP + i0 + i] = acc[dd];
  }
}

// ---------------- output projection: 800 blocks, 2 couts/thread ------------
__global__ __launch_bounds__(256) void k_proj(
    const float* __restrict__ inner, const float* __restrict__ w,
    const float* __restrict__ bo, float* __restrict__ out) {
  int oc = blockIdx.x & 31;              // 32 o-chunks of 8
  int pt = blockIdx.x >> 5;              // 25 p-tiles of 64
  int t = threadIdx.x;
  int quad = __builtin_amdgcn_readfirstlane(t >> 6);  // wave-uniform
  int o0 = oc * 8 + quad * 2;
  int p = pt * 64 + (t & 63);
  const float* w0r = w + (size_t)o0 * 512;   // wave-uniform -> scalar loads
  float a0 = 0.f, a1 = 0.f;
#pragma unroll 8
  for (int c = 0; c < 512; ++c) {
    float xv = inner[c * NP + p];
    a0 = fmaf(w0r[c], xv, a0);
    a1 = fmaf(w0r[512 + c], xv, a1);
  }
  out[(o0 + 0) * NP + p] = a0 + bo[o0 + 0];
  out[(o0 + 1) * NP + p] = a1 + bo[o0 + 1];
}

extern "C" void kernel_launch(void* const* d_in, const int* in_sizes, int n_in,
                              void* d_out, int out_size, void* d_ws, size_t ws_size,
                              hipStream_t stream) {
  int L = in_sizes[1] / (512 * 32);
  int l = L - 1;
  const float* x      = (const float*)d_in[0];
  const float* wq     = (const float*)d_in[1]  + (size_t)l * 512 * 32;
  const float* wk     = (const float*)d_in[2]  + (size_t)l * 512 * 32;
  const float* wv     = (const float*)d_in[3]  + (size_t)l * 512 * 32;
  const float* w_off1 = (const float*)d_in[4]  + (size_t)l * 64 * 36;
  const float* b_off1 = (const float*)d_in[5]  + (size_t)l * 64;
  const float* w_off2 = (const float*)d_in[6]  + (size_t)l * 2 * 64;
  const float* cpb_w0 = (const float*)d_in[7]  + (size_t)l * 64 * 2;
  const float* cpb_b0 = (const float*)d_in[8]  + (size_t)l * 64;
  const float* cpb_w1 = (const float*)d_in[9]  + (size_t)l * 64 * 64;
  const float* cpb_b1 = (const float*)d_in[10] + (size_t)l * 64;
  const float* cpb_w2 = (const float*)d_in[11] + (size_t)l * 64;
  const float* cpb_b2 = (const float*)d_in[12] + (size_t)l * 1;
  const float* w_out  = (const float*)d_in[13] + (size_t)l * 256 * 512;
  const float* b_out  = (const float*)d_in[14] + (size_t)l * 256;
  float* out = (float*)d_out;

  float* ws = (float*)d_ws;
  float*    q_ws    = ws;               // 819200
  float*    qt_ws   = ws + 819200;      // 819200 (transposed [p][512])
  float*    k_ws    = ws + 1638400;     // 51200
  float*    vt_ws   = ws + 1689600;     // 51200 (transposed [gj][c])
  _Float16* bias16  = (_Float16*)(ws + 1740800);  // 1280000 halves = 640000 f
  float*    inner   = ws + 2380800;     // 819200  (end 3,200,000 f = 12.8 MB)

  k_conv1x1<<<320, 256, 0, stream>>>(x, wq, q_ws, qt_ws);
  k_off_cpb<<<800, 256, 0, stream>>>(qt_ws, w_off1, b_off1, w_off2, x, wk, wv,
                                     cpb_w0, cpb_b0, cpb_w1, cpb_b1, cpb_w2,
                                     cpb_b2, k_ws, vt_ws, bias16);
  k_attn<<<800, 256, 0, stream>>>(q_ws, k_ws, vt_ws, bias16, inner);
  k_proj<<<800, 256, 0, stream>>>(inner, w_out, b_out, out);
}